// Round 17
// baseline (168.930 us; speedup 1.0000x reference)
//
#include <hip/hip_runtime.h>

#define N_NODES 100000
#define N_EDGES 1600000
#define IN_F 128
#define H_F 64
#define ZROW N_NODES    // zero sentinel row index in gather tables

#define BSH 10          // coarse bucket = dst >> 10
#define BNODES 1024     // nodes per bucket
#define NBKT 98         // ceil(100000 / 1024)
#define EPB 4096        // edges per block in coarse scatter
#define BCAP 20000      // slack capacity per coarse bucket in tmp (mean 16327, +29 sigma)
#define SCAP 28192      // slack capacity per bucket in sorted (BCAP + 1024*8 pad)

#define NSLICE 4
#define SLICE_ELEMS ((size_t)(N_NODES + 16) * 16)   // shorts per slice (row = 16 bf16 = 32 B)

typedef short short8 __attribute__((ext_vector_type(8)));
typedef float floatx4 __attribute__((ext_vector_type(4)));

union U16x8 { short8 v; unsigned short us[8]; unsigned int u[4]; };

// ---- bf16 helpers ----
static __device__ __forceinline__ unsigned short f2bf(float f) {
    unsigned int u = __float_as_uint(f);
    unsigned int r = (u + 0x7FFFu + ((u >> 16) & 1u)) >> 16;
    return (unsigned short)r;
}
static __device__ __forceinline__ float bflo(unsigned int u) {
    return __uint_as_float(u << 16);
}
static __device__ __forceinline__ float bfhi(unsigned int u) {
    return __uint_as_float(u & 0xFFFF0000u);
}
static __device__ __forceinline__ unsigned int pk2(float a, float b) {
    return (unsigned int)f2bf(a) | ((unsigned int)f2bf(b) << 16);
}

// ---------------- fused init + W fragment pre-pack ----------------
__global__ __launch_bounds__(256) void initwpack_kernel(const float* __restrict__ W,
                                                        unsigned int* __restrict__ wfrag,
                                                        int* __restrict__ ccur,
                                                        unsigned short* __restrict__ h1sS) {
    int i = blockIdx.x * 256 + threadIdx.x;   // [0, 8192)
    int reg = i & 3, lane = (i >> 2) & 63, fkc = i >> 8;
    int ct = fkc >> 2, kc = fkc & 3;
    int fcol = ct * 16 + (lane & 15);
    int k = kc * 32 + (lane >> 4) * 8 + reg * 2;
    wfrag[i] = pk2(W[k * 64 + fcol], W[(k + 1) * 64 + fcol]);

    if (blockIdx.x == 0) {
        int t = threadIdx.x;
        if (t < NBKT) ccur[t] = t * BCAP;
        if (t < 32) {  // zero h1s sentinel rows: 4 slices x 8 uints
            unsigned int* w = (unsigned int*)(h1sS + (size_t)(t >> 3) * SLICE_ELEMS
                                              + (size_t)ZROW * 16);
            w[t & 7] = 0;
        }
    }
}

// ---------------- pass 1: coarse scatter into slack buckets ----------------
__global__ __launch_bounds__(256) void coarse_scatter_kernel(const int* __restrict__ src,
                                                             const int* __restrict__ dst,
                                                             int* __restrict__ ccur,
                                                             unsigned int* __restrict__ tmp, int E) {
    __shared__ unsigned int buf[EPB];               // 16 KB
    __shared__ unsigned char bktA[EPB];             // 4 KB
    __shared__ int cnt[NBKT], lofs[NBKT], gofs[NBKT];
    int base = blockIdx.x * EPB;
    int n = E - base; if (n > EPB) n = EPB;

    for (int i = threadIdx.x; i < NBKT; i += 256) cnt[i] = 0;
    __syncthreads();

    unsigned int v[16]; int bk[16], loc[16];
    #pragma unroll
    for (int j = 0; j < 16; ++j) {
        int o = threadIdx.x + j * 256;
        bk[j] = -1;
        if (o < n) {
            int s = src[base + o];
            int d = dst[base + o];
            bk[j]  = d >> BSH;
            v[j]   = ((unsigned int)(d & (BNODES - 1)) << 17) | (unsigned int)s;
            loc[j] = atomicAdd(&cnt[bk[j]], 1);
        }
    }
    __syncthreads();
    if (threadIdx.x == 0) {
        int run = 0;
        for (int b = 0; b < NBKT; ++b) { lofs[b] = run; run += cnt[b]; }
    }
    __syncthreads();
    if (threadIdx.x < NBKT && cnt[threadIdx.x] > 0)
        gofs[threadIdx.x] = atomicAdd(&ccur[threadIdx.x], cnt[threadIdx.x]);
    __syncthreads();
    #pragma unroll
    for (int j = 0; j < 16; ++j)
        if (bk[j] >= 0) {
            int p = lofs[bk[j]] + loc[j];
            buf[p]  = v[j];
            bktA[p] = (unsigned char)bk[j];
        }
    __syncthreads();
    for (int i = threadIdx.x; i < n; i += 256) {
        int b = bktA[i];
        tmp[gofs[b] + (i - lofs[b])] = buf[i];
    }
}

// ---------------- pass 2: per-bucket LDS pipeline, PADDED CSR output ----------------
// meta[d] = start_index | (padded_len/8 << 22)
__global__ __launch_bounds__(512) void bucket_kernel(const unsigned int* __restrict__ tmp,
                                                     const int* __restrict__ ccur,
                                                     unsigned int* __restrict__ meta,
                                                     int* __restrict__ sorted_src,
                                                     float* __restrict__ dinv1,
                                                     float* __restrict__ dinv2, int N) {
    __shared__ int cnt[BNODES];
    __shared__ int sd[512];
    int b   = blockIdx.x;
    int tid = threadIdx.x;
    int tbeg = b * BCAP, tend = ccur[b];   // bucket's run in tmp (slack layout)
    int sbase = b * SCAP;                  // bucket's region in sorted_src

    for (int i = tid; i < BNODES; i += 512) cnt[i] = 0;
    __syncthreads();
    for (int i = tbeg + tid; i < tend; i += 512)
        atomicAdd(&cnt[tmp[i] >> 17], 1);
    __syncthreads();

    int c0 = cnt[2 * tid], c1 = cnt[2 * tid + 1];
    int p0 = (c0 + 7) & ~7, p1 = (c1 + 7) & ~7;   // padded lengths
    int s  = p0 + p1;
    sd[tid] = s;
    __syncthreads();
    for (int off = 1; off < 512; off <<= 1) {
        int t = (tid >= off) ? sd[tid - off] : 0;
        __syncthreads();
        sd[tid] += t;
        __syncthreads();
    }
    int ex = sd[tid] - s;
    int g0 = sbase + ex, g1 = sbase + ex + p0;

    int node0 = b * BNODES + 2 * tid;
    if (node0 < N) {
        meta[node0] = (unsigned int)g0 | ((unsigned int)(p0 >> 3) << 22);
        dinv1[node0] = rsqrtf((float)(c0 + 1));
        dinv2[node0] = c0 ? rsqrtf((float)c0) : 0.0f;
        for (int k = c0; k < p0; ++k) sorted_src[g0 + k] = ZROW;   // pad fill
    }
    if (node0 + 1 < N) {
        meta[node0 + 1] = (unsigned int)g1 | ((unsigned int)(p1 >> 3) << 22);
        dinv1[node0 + 1] = rsqrtf((float)(c1 + 1));
        dinv2[node0 + 1] = c1 ? rsqrtf((float)c1) : 0.0f;
        for (int k = c1; k < p1; ++k) sorted_src[g1 + k] = ZROW;   // pad fill
    }
    __syncthreads();
    cnt[2 * tid] = g0;                     // absolute cursors
    cnt[2 * tid + 1] = g1;
    __syncthreads();

    for (int i = tbeg + tid; i < tend; i += 512) {
        unsigned int v = tmp[i];
        int p = atomicAdd(&cnt[v >> 17], 1);
        sorted_src[p] = (int)(v & 0x1FFFFu);
    }
}

// ---------------- MFMA GEMM: XsS[ct][node][16] = bf16((A @ W1) * dinv1) ----------------
__global__ __launch_bounds__(256) void gemm_kernel(const float* __restrict__ A,
                                                   const uint4* __restrict__ wfrag,
                                                   const float* __restrict__ dinv1,
                                                   unsigned short* __restrict__ XsS, int nTiles) {
    // block 0: zero Xs sentinel rows (tmp aliased them; tmp is dead now)
    if (blockIdx.x == 0 && threadIdx.x < 32) {
        int t = threadIdx.x;
        unsigned int* w = (unsigned int*)(XsS + (size_t)(t >> 3) * SLICE_ELEMS
                                          + (size_t)ZROW * 16);
        w[t & 7] = 0;
    }

    int wid = blockIdx.x * 4 + (threadIdx.x >> 6);
    int lane = threadIdx.x & 63;
    int lrow = lane & 15, lk = lane >> 4;

    short8 wf[16];
    #pragma unroll
    for (int i = 0; i < 16; ++i)
        wf[i] = *reinterpret_cast<const short8*>(&wfrag[i * 64 + lane]);

    #pragma unroll
    for (int tt = 0; tt < 4; ++tt) {
        int t = wid * 4 + tt;
        if (t >= nTiles) break;
        int node = t * 16 + lrow;
        const float4* ap = reinterpret_cast<const float4*>(A + (size_t)node * IN_F);

        short8 af[4];
        #pragma unroll
        for (int kc = 0; kc < 4; ++kc) {
            float4 x = ap[kc * 8 + lk * 2];
            float4 y = ap[kc * 8 + lk * 2 + 1];
            U16x8 u;
            u.us[0] = f2bf(x.x); u.us[1] = f2bf(x.y); u.us[2] = f2bf(x.z); u.us[3] = f2bf(x.w);
            u.us[4] = f2bf(y.x); u.us[5] = f2bf(y.y); u.us[6] = f2bf(y.z); u.us[7] = f2bf(y.w);
            af[kc] = u.v;
        }

        float dv = dinv1[node];
        #pragma unroll
        for (int ct = 0; ct < 4; ++ct) {
            floatx4 acc = {0.f, 0.f, 0.f, 0.f};
            acc = __builtin_amdgcn_mfma_f32_16x16x32_bf16(wf[ct * 4 + 0], af[0], acc, 0, 0, 0);
            acc = __builtin_amdgcn_mfma_f32_16x16x32_bf16(wf[ct * 4 + 1], af[1], acc, 0, 0, 0);
            acc = __builtin_amdgcn_mfma_f32_16x16x32_bf16(wf[ct * 4 + 2], af[2], acc, 0, 0, 0);
            acc = __builtin_amdgcn_mfma_f32_16x16x32_bf16(wf[ct * 4 + 3], af[3], acc, 0, 0, 0);
            uint2 o;
            o.x = pk2(acc[0] * dv, acc[1] * dv);
            o.y = pk2(acc[2] * dv, acc[3] * dv);
            // slice = ct; within-slice feats lk*4..lk*4+3
            *reinterpret_cast<uint2*>(XsS + (size_t)ct * SLICE_ELEMS + (size_t)node * 16 + lk * 4) = o;
        }
    }
}

// ---------------- prop1 (sliced): h1S = dinv1*(sum XsS[s] + XsS[d]); h1sS = h1S*dinv2 ----------------
// grid = NSLICE * pblocks blocks; slice varies slowest (temporal L2 residency per slice).
// wave: 4 nodes (16-lane groups); lane j: edge-sub j>>2, feat-quad j&3 (8 B of 32 B row).
__global__ __launch_bounds__(256) void prop1_kernel(const unsigned int* __restrict__ meta,
                                                    const int* __restrict__ sorted_src,
                                                    const unsigned short* __restrict__ XsS,
                                                    const float* __restrict__ dinv1,
                                                    const float* __restrict__ dinv2,
                                                    unsigned short* __restrict__ h1S,
                                                    unsigned short* __restrict__ h1sS,
                                                    int N, int pblocks) {
    int slice = blockIdx.x / pblocks;
    int bx    = blockIdx.x - slice * pblocks;
    int wid   = bx * 4 + (threadIdx.x >> 6);
    int lane  = threadIdx.x & 63;
    int g  = lane >> 4, j = lane & 15;
    int es = j >> 2;
    unsigned bo = (unsigned)((j & 3) << 3);   // byte offset in 32 B row
    int d = wid * 4 + g;
    bool active = d < N;
    int dd = active ? d : N - 1;

    unsigned int m = meta[dd];
    int beg = (int)(m & 0x3FFFFFu);
    int nit = (int)(m >> 22);
    const int* idp = sorted_src + beg;
    const char* XB = (const char*)(XsS + (size_t)slice * SLICE_ELEMS);
    float c0 = 0.f, c1 = 0.f, c2 = 0.f, c3 = 0.f;

    int it = 0;
    for (; it + 2 <= nit; it += 2, idp += 16) {   // 16 edges, MLP 4/lane
        int s0 = idp[es], s1 = idp[4 + es], s2 = idp[8 + es], s3 = idp[12 + es];
        uint2 v0 = *reinterpret_cast<const uint2*>(XB + (((unsigned)s0 << 5) + bo));
        uint2 v1 = *reinterpret_cast<const uint2*>(XB + (((unsigned)s1 << 5) + bo));
        uint2 v2 = *reinterpret_cast<const uint2*>(XB + (((unsigned)s2 << 5) + bo));
        uint2 v3 = *reinterpret_cast<const uint2*>(XB + (((unsigned)s3 << 5) + bo));
        c0 += bflo(v0.x); c1 += bfhi(v0.x); c2 += bflo(v0.y); c3 += bfhi(v0.y);
        c0 += bflo(v1.x); c1 += bfhi(v1.x); c2 += bflo(v1.y); c3 += bfhi(v1.y);
        c0 += bflo(v2.x); c1 += bfhi(v2.x); c2 += bflo(v2.y); c3 += bfhi(v2.y);
        c0 += bflo(v3.x); c1 += bfhi(v3.x); c2 += bflo(v3.y); c3 += bfhi(v3.y);
    }
    if (it < nit) {                               // 8-edge tail
        int s0 = idp[es], s1 = idp[4 + es];
        uint2 v0 = *reinterpret_cast<const uint2*>(XB + (((unsigned)s0 << 5) + bo));
        uint2 v1 = *reinterpret_cast<const uint2*>(XB + (((unsigned)s1 << 5) + bo));
        c0 += bflo(v0.x); c1 += bfhi(v0.x); c2 += bflo(v0.y); c3 += bfhi(v0.y);
        c0 += bflo(v1.x); c1 += bfhi(v1.x); c2 += bflo(v1.y); c3 += bfhi(v1.y);
    }

    // reduce across edge-subs (fixed feat-quad): xor 4, then 8
    c0 += __shfl_xor(c0, 4); c1 += __shfl_xor(c1, 4);
    c2 += __shfl_xor(c2, 4); c3 += __shfl_xor(c3, 4);
    c0 += __shfl_xor(c0, 8); c1 += __shfl_xor(c1, 8);
    c2 += __shfl_xor(c2, 8); c3 += __shfl_xor(c3, 8);

    float dv  = dinv1[dd];
    float dv2 = dinv2[dd];
    uint2 sv = *reinterpret_cast<const uint2*>(XB + (((unsigned)dd << 5) + bo));
    float h0  = dv * (c0 + bflo(sv.x));
    float h1v = dv * (c1 + bfhi(sv.x));
    float h2  = dv * (c2 + bflo(sv.y));
    float h3  = dv * (c3 + bfhi(sv.y));
    if (active && es == 0) {
        char* HB  = (char*)h1S  + (size_t)slice * SLICE_ELEMS * 2;
        char* HSB = (char*)h1sS + (size_t)slice * SLICE_ELEMS * 2;
        uint2 o1; o1.x = pk2(h0, h1v); o1.y = pk2(h2, h3);
        *reinterpret_cast<uint2*>(HB + (((unsigned)d << 5) + bo)) = o1;
        uint2 o2; o2.x = pk2(h0 * dv2, h1v * dv2); o2.y = pk2(h2 * dv2, h3 * dv2);
        *reinterpret_cast<uint2*>(HSB + (((unsigned)d << 5) + bo)) = o2;
    }
}

// ---------------- prop2 (sliced): out = a0*h1 + a1*dinv2*sum(h1sS[s]) ----------------
__global__ __launch_bounds__(256) void prop2_kernel(const unsigned int* __restrict__ meta,
                                                    const int* __restrict__ sorted_src,
                                                    const unsigned short* __restrict__ h1S,
                                                    const unsigned short* __restrict__ h1sS,
                                                    const float* __restrict__ dinv2,
                                                    const float* __restrict__ alphas,
                                                    float* __restrict__ out,
                                                    int N, int pblocks) {
    int slice = blockIdx.x / pblocks;
    int bx    = blockIdx.x - slice * pblocks;
    int wid   = bx * 4 + (threadIdx.x >> 6);
    int lane  = threadIdx.x & 63;
    int g  = lane >> 4, j = lane & 15;
    int es = j >> 2;
    unsigned bo = (unsigned)((j & 3) << 3);
    int d = wid * 4 + g;
    bool active = d < N;
    int dd = active ? d : N - 1;

    float e0 = expf(alphas[0]), e1 = expf(alphas[1]);
    float aw0 = e0 / (e0 + e1), aw1 = e1 / (e0 + e1);

    unsigned int m = meta[dd];
    int beg = (int)(m & 0x3FFFFFu);
    int nit = (int)(m >> 22);
    const int* idp = sorted_src + beg;
    const char* HSB = (const char*)(h1sS + (size_t)slice * SLICE_ELEMS);
    float c0 = 0.f, c1 = 0.f, c2 = 0.f, c3 = 0.f;

    int it = 0;
    for (; it + 2 <= nit; it += 2, idp += 16) {
        int s0 = idp[es], s1 = idp[4 + es], s2 = idp[8 + es], s3 = idp[12 + es];
        uint2 v0 = *reinterpret_cast<const uint2*>(HSB + (((unsigned)s0 << 5) + bo));
        uint2 v1 = *reinterpret_cast<const uint2*>(HSB + (((unsigned)s1 << 5) + bo));
        uint2 v2 = *reinterpret_cast<const uint2*>(HSB + (((unsigned)s2 << 5) + bo));
        uint2 v3 = *reinterpret_cast<const uint2*>(HSB + (((unsigned)s3 << 5) + bo));
        c0 += bflo(v0.x); c1 += bfhi(v0.x); c2 += bflo(v0.y); c3 += bfhi(v0.y);
        c0 += bflo(v1.x); c1 += bfhi(v1.x); c2 += bflo(v1.y); c3 += bfhi(v1.y);
        c0 += bflo(v2.x); c1 += bfhi(v2.x); c2 += bflo(v2.y); c3 += bfhi(v2.y);
        c0 += bflo(v3.x); c1 += bfhi(v3.x); c2 += bflo(v3.y); c3 += bfhi(v3.y);
    }
    if (it < nit) {
        int s0 = idp[es], s1 = idp[4 + es];
        uint2 v0 = *reinterpret_cast<const uint2*>(HSB + (((unsigned)s0 << 5) + bo));
        uint2 v1 = *reinterpret_cast<const uint2*>(HSB + (((unsigned)s1 << 5) + bo));
        c0 += bflo(v0.x); c1 += bfhi(v0.x); c2 += bflo(v0.y); c3 += bfhi(v0.y);
        c0 += bflo(v1.x); c1 += bfhi(v1.x); c2 += bflo(v1.y); c3 += bfhi(v1.y);
    }

    c0 += __shfl_xor(c0, 4); c1 += __shfl_xor(c1, 4);
    c2 += __shfl_xor(c2, 4); c3 += __shfl_xor(c3, 4);
    c0 += __shfl_xor(c0, 8); c1 += __shfl_xor(c1, 8);
    c2 += __shfl_xor(c2, 8); c3 += __shfl_xor(c3, 8);

    if (active && es == 0) {
        float sa1 = aw1 * dinv2[dd];
        const char* HB = (const char*)(h1S + (size_t)slice * SLICE_ELEMS);
        uint2 sv = *reinterpret_cast<const uint2*>(HB + (((unsigned)d << 5) + bo));
        float4 o;
        o.x = aw0 * bflo(sv.x) + sa1 * c0;
        o.y = aw0 * bfhi(sv.x) + sa1 * c1;
        o.z = aw0 * bflo(sv.y) + sa1 * c2;
        o.w = aw0 * bfhi(sv.y) + sa1 * c3;
        *reinterpret_cast<float4*>(out + (size_t)d * H_F + slice * 16 + (j & 3) * 4) = o;
    }
}

extern "C" void kernel_launch(void* const* d_in, const int* in_sizes, int n_in,
                              void* d_out, int out_size, void* d_ws, size_t ws_size,
                              hipStream_t stream) {
    const int*   edge_index = (const int*)d_in[0];   // [2, E]
    const float* in_feat    = (const float*)d_in[1]; // [N, 128]
    const float* W1         = (const float*)d_in[2]; // [128, 64]
    const float* alphas     = (const float*)d_in[3]; // [2]
    float*       out        = (float*)d_out;         // [N, 64]

    const int* src = edge_index;
    const int* dst = edge_index + N_EDGES;

    // workspace layout: sliced bf16 tables [4][N+16][16], row N = zero sentinel per slice
    char* ws = (char*)d_ws;
    size_t tabBytes = (size_t)NSLICE * SLICE_ELEMS * 2;          // 12.8 MB
    unsigned short* XsS  = (unsigned short*)(ws);
    unsigned int*   tmp  = (unsigned int*)(ws);                  // 7.84 MB — aliases XsS (dead until gemm)
    unsigned short* h1S  = (unsigned short*)(ws + tabBytes);
    unsigned short* h1sS = (unsigned short*)(ws + 2 * tabBytes);
    char* p = ws + 3 * tabBytes;
    int*   sorted = (int*)p;   p += (size_t)NBKT * SCAP * 4;     // 11.05 MB (per-bucket slack)
    unsigned int* meta = (unsigned int*)p; p += (size_t)(N_NODES + 4) * 4;
    float* dinv1  = (float*)p; p += (size_t)N_NODES * 4;
    float* dinv2  = (float*)p; p += (size_t)N_NODES * 4;
    int*   ccur   = (int*)p;   p += (size_t)NBKT * 4;
    unsigned int* wfrag = (unsigned int*)p; p += 8192 * 4;       // 32 KB packed W frags

    initwpack_kernel<<<32, 256, 0, stream>>>(W1, wfrag, ccur, h1sS);
    coarse_scatter_kernel<<<(N_EDGES + EPB - 1) / EPB, 256, 0, stream>>>(src, dst, ccur, tmp, N_EDGES);
    bucket_kernel<<<NBKT, 512, 0, stream>>>(tmp, ccur, meta, sorted, dinv1, dinv2, N_NODES);

    // gemm after bucket_kernel (tmp aliases XsS; also zeroes XsS sentinels)
    int nTiles = N_NODES / 16;                        // 6250
    int gemm_waves = (nTiles + 3) / 4;                // 1563
    gemm_kernel<<<(gemm_waves + 3) / 4, 256, 0, stream>>>(in_feat, (const uint4*)wfrag, dinv1, XsS, nTiles);

    int pwaves  = (N_NODES + 3) / 4;                  // 25000 waves, 4 nodes each
    int pblocks = (pwaves + 3) / 4;                   // 6250 blocks per slice
    prop1_kernel<<<NSLICE * pblocks, 256, 0, stream>>>(meta, sorted, XsS, dinv1, dinv2,
                                                       h1S, h1sS, N_NODES, pblocks);
    prop2_kernel<<<NSLICE * pblocks, 256, 0, stream>>>(meta, sorted, h1S, h1sS, dinv2,
                                                       alphas, out, N_NODES, pblocks);
}

// Round 18
// 129.460 us; speedup vs baseline: 1.3049x; 1.3049x over previous
//
#include <hip/hip_runtime.h>

#define N_NODES 100000
#define N_EDGES 1600000
#define IN_F 128
#define H_F 64
#define ZROW N_NODES    // zero sentinel row index in gather tables

#define BSH 10          // coarse bucket = dst >> 10
#define BNODES 1024     // nodes per bucket
#define NBKT 98         // ceil(100000 / 1024)
#define EPB 4096        // edges per block in coarse scatter
#define BCAP 20000      // slack capacity per coarse bucket in tmp (mean 16327, +29 sigma)
#define SCAP 28192      // slack capacity per bucket in sorted (BCAP + 1024*8 pad)

typedef short short8 __attribute__((ext_vector_type(8)));
typedef float floatx4 __attribute__((ext_vector_type(4)));

union U16x8 { short8 v; unsigned short us[8]; unsigned int u[4]; };

// ---- bf16 helpers ----
static __device__ __forceinline__ unsigned short f2bf(float f) {
    unsigned int u = __float_as_uint(f);
    unsigned int r = (u + 0x7FFFu + ((u >> 16) & 1u)) >> 16;
    return (unsigned short)r;
}
static __device__ __forceinline__ float bflo(unsigned int u) {
    return __uint_as_float(u << 16);
}
static __device__ __forceinline__ float bfhi(unsigned int u) {
    return __uint_as_float(u & 0xFFFF0000u);
}
static __device__ __forceinline__ unsigned int pk2(float a, float b) {
    return (unsigned int)f2bf(a) | ((unsigned int)f2bf(b) << 16);
}

// ---------------- fused init + W fragment pre-pack ----------------
__global__ __launch_bounds__(256) void initwpack_kernel(const float* __restrict__ W,
                                                        unsigned int* __restrict__ wfrag,
                                                        int* __restrict__ ccur,
                                                        unsigned int* __restrict__ XsZ,
                                                        unsigned int* __restrict__ h1sZ) {
    int i = blockIdx.x * 256 + threadIdx.x;   // [0, 8192)
    int reg = i & 3, lane = (i >> 2) & 63, fkc = i >> 8;
    int ct = fkc >> 2, kc = fkc & 3;
    int fcol = ct * 16 + (lane & 15);
    int k = kc * 32 + (lane >> 4) * 8 + reg * 2;
    wfrag[i] = pk2(W[k * 64 + fcol], W[(k + 1) * 64 + fcol]);

    if (blockIdx.x == 0) {
        int t = threadIdx.x;
        if (t < NBKT) ccur[t] = t * BCAP;
        if (t < 32) XsZ[t] = 0;                 // Xs sentinel row (64 bf16 = 32 uints)
        else if (t < 64) h1sZ[t - 32] = 0;      // h1s sentinel row
    }
}

// ---------------- pass 1: coarse scatter into slack buckets ----------------
__global__ __launch_bounds__(256) void coarse_scatter_kernel(const int* __restrict__ src,
                                                             const int* __restrict__ dst,
                                                             int* __restrict__ ccur,
                                                             unsigned int* __restrict__ tmp, int E) {
    __shared__ unsigned int buf[EPB];               // 16 KB
    __shared__ unsigned char bktA[EPB];             // 4 KB
    __shared__ int cnt[NBKT], lofs[NBKT], gofs[NBKT];
    int base = blockIdx.x * EPB;
    int n = E - base; if (n > EPB) n = EPB;

    for (int i = threadIdx.x; i < NBKT; i += 256) cnt[i] = 0;
    __syncthreads();

    unsigned int v[16]; int bk[16], loc[16];
    #pragma unroll
    for (int j = 0; j < 16; ++j) {
        int o = threadIdx.x + j * 256;
        bk[j] = -1;
        if (o < n) {
            int s = src[base + o];
            int d = dst[base + o];
            bk[j]  = d >> BSH;
            v[j]   = ((unsigned int)(d & (BNODES - 1)) << 17) | (unsigned int)s;
            loc[j] = atomicAdd(&cnt[bk[j]], 1);
        }
    }
    __syncthreads();
    if (threadIdx.x == 0) {
        int run = 0;
        for (int b = 0; b < NBKT; ++b) { lofs[b] = run; run += cnt[b]; }
    }
    __syncthreads();
    if (threadIdx.x < NBKT && cnt[threadIdx.x] > 0)
        gofs[threadIdx.x] = atomicAdd(&ccur[threadIdx.x], cnt[threadIdx.x]);
    __syncthreads();
    #pragma unroll
    for (int j = 0; j < 16; ++j)
        if (bk[j] >= 0) {
            int p = lofs[bk[j]] + loc[j];
            buf[p]  = v[j];
            bktA[p] = (unsigned char)bk[j];
        }
    __syncthreads();
    for (int i = threadIdx.x; i < n; i += 256) {
        int b = bktA[i];
        tmp[gofs[b] + (i - lofs[b])] = buf[i];
    }
}

// ---------------- pass 2: per-bucket LDS pipeline, PADDED CSR output ----------------
// Each bucket owns sorted region [b*SCAP, ...). Per node: edges padded to mult of 8
// with ZROW entries. offsets[d] = start; npad8[d] = padded_len/8.
__global__ __launch_bounds__(512) void bucket_kernel(const unsigned int* __restrict__ tmp,
                                                     const int* __restrict__ ccur,
                                                     int* __restrict__ offsets,
                                                     unsigned char* __restrict__ npad8,
                                                     int* __restrict__ sorted_src,
                                                     float* __restrict__ dinv1,
                                                     float* __restrict__ dinv2, int N) {
    __shared__ int cnt[BNODES];
    __shared__ int sd[512];
    int b   = blockIdx.x;
    int tid = threadIdx.x;
    int tbeg = b * BCAP, tend = ccur[b];   // bucket's run in tmp (slack layout)
    int sbase = b * SCAP;                  // bucket's region in sorted_src

    for (int i = tid; i < BNODES; i += 512) cnt[i] = 0;
    __syncthreads();
    for (int i = tbeg + tid; i < tend; i += 512)
        atomicAdd(&cnt[tmp[i] >> 17], 1);
    __syncthreads();

    int c0 = cnt[2 * tid], c1 = cnt[2 * tid + 1];
    int p0 = (c0 + 7) & ~7, p1 = (c1 + 7) & ~7;   // padded lengths
    int s  = p0 + p1;
    sd[tid] = s;
    __syncthreads();
    for (int off = 1; off < 512; off <<= 1) {
        int t = (tid >= off) ? sd[tid - off] : 0;
        __syncthreads();
        sd[tid] += t;
        __syncthreads();
    }
    int ex = sd[tid] - s;
    int g0 = sbase + ex, g1 = sbase + ex + p0;

    int node0 = b * BNODES + 2 * tid;
    if (node0 < N) {
        offsets[node0] = g0;
        npad8[node0] = (unsigned char)(p0 >> 3);
        dinv1[node0] = rsqrtf((float)(c0 + 1));
        dinv2[node0] = c0 ? rsqrtf((float)c0) : 0.0f;
        for (int k = c0; k < p0; ++k) sorted_src[g0 + k] = ZROW;   // pad fill
    }
    if (node0 + 1 < N) {
        offsets[node0 + 1] = g1;
        npad8[node0 + 1] = (unsigned char)(p1 >> 3);
        dinv1[node0 + 1] = rsqrtf((float)(c1 + 1));
        dinv2[node0 + 1] = c1 ? rsqrtf((float)c1) : 0.0f;
        for (int k = c1; k < p1; ++k) sorted_src[g1 + k] = ZROW;   // pad fill
    }
    __syncthreads();
    cnt[2 * tid] = g0;                     // absolute cursors
    cnt[2 * tid + 1] = g1;
    __syncthreads();

    for (int i = tbeg + tid; i < tend; i += 512) {
        unsigned int v = tmp[i];
        int p = atomicAdd(&cnt[v >> 17], 1);
        sorted_src[p] = (int)(v & 0x1FFFFu);
    }
}

// ---------------- MFMA GEMM: Xs = bf16((in_feat @ W1) * dinv1), 4 tiles/wave ----------------
__global__ __launch_bounds__(256) void gemm_kernel(const float* __restrict__ A,
                                                   const uint4* __restrict__ wfrag,
                                                   const float* __restrict__ dinv1,
                                                   unsigned short* __restrict__ Xs, int nTiles) {
    int wid = blockIdx.x * 4 + (threadIdx.x >> 6);
    int lane = threadIdx.x & 63;
    int lrow = lane & 15, lk = lane >> 4;

    short8 wf[16];
    #pragma unroll
    for (int i = 0; i < 16; ++i)
        wf[i] = *reinterpret_cast<const short8*>(&wfrag[i * 64 + lane]);

    #pragma unroll
    for (int tt = 0; tt < 4; ++tt) {
        int t = wid * 4 + tt;
        if (t >= nTiles) break;
        int node = t * 16 + lrow;
        const float4* ap = reinterpret_cast<const float4*>(A + (size_t)node * IN_F);

        short8 af[4];
        #pragma unroll
        for (int kc = 0; kc < 4; ++kc) {
            float4 x = ap[kc * 8 + lk * 2];
            float4 y = ap[kc * 8 + lk * 2 + 1];
            U16x8 u;
            u.us[0] = f2bf(x.x); u.us[1] = f2bf(x.y); u.us[2] = f2bf(x.z); u.us[3] = f2bf(x.w);
            u.us[4] = f2bf(y.x); u.us[5] = f2bf(y.y); u.us[6] = f2bf(y.z); u.us[7] = f2bf(y.w);
            af[kc] = u.v;
        }

        float dv = dinv1[node];
        #pragma unroll
        for (int ct = 0; ct < 4; ++ct) {
            floatx4 acc = {0.f, 0.f, 0.f, 0.f};
            acc = __builtin_amdgcn_mfma_f32_16x16x32_bf16(wf[ct * 4 + 0], af[0], acc, 0, 0, 0);
            acc = __builtin_amdgcn_mfma_f32_16x16x32_bf16(wf[ct * 4 + 1], af[1], acc, 0, 0, 0);
            acc = __builtin_amdgcn_mfma_f32_16x16x32_bf16(wf[ct * 4 + 2], af[2], acc, 0, 0, 0);
            acc = __builtin_amdgcn_mfma_f32_16x16x32_bf16(wf[ct * 4 + 3], af[3], acc, 0, 0, 0);
            uint2 o;
            o.x = pk2(acc[0] * dv, acc[1] * dv);
            o.y = pk2(acc[2] * dv, acc[3] * dv);
            *reinterpret_cast<uint2*>(Xs + (size_t)node * H_F + ct * 16 + lk * 4) = o;
        }
    }
}

// ---------------- prop1: 4 nodes/wave, padded CSR, direct uniform id loads ----------------
// h1[d] = dinv1[d]*(sum Xs[s] + Xs[d]);  h1s[d] = h1[d]*dinv2[d]
__global__ __launch_bounds__(256) void prop1_kernel(const int* __restrict__ offsets,
                                                    const unsigned char* __restrict__ npad8,
                                                    const int* __restrict__ sorted_src,
                                                    const unsigned short* __restrict__ Xs,
                                                    const float* __restrict__ dinv1,
                                                    const float* __restrict__ dinv2,
                                                    unsigned short* __restrict__ h1,
                                                    unsigned short* __restrict__ h1s, int N) {
    int wid  = (blockIdx.x * blockDim.x + threadIdx.x) >> 6;
    int lane = threadIdx.x & 63;
    int g = lane >> 4, fl = lane & 15;
    int d = wid * 4 + g;
    bool active = d < N;
    int dd = active ? d : N - 1;

    int beg = offsets[dd];
    int nit = npad8[dd];
    const int* idp = sorted_src + beg;
    const char* XsB = (const char*)Xs;
    unsigned bo = (unsigned)(fl << 3);          // byte offset within 128B row
    float c0 = 0.f, c1 = 0.f, c2 = 0.f, c3 = 0.f;

    for (int it = 0; it < nit; ++it, idp += 8) {
        int s[8]; uint2 v[8];
        #pragma unroll
        for (int j = 0; j < 8; ++j) s[j] = idp[j];          // group-uniform, L1 broadcast
        #pragma unroll
        for (int j = 0; j < 8; ++j)
            v[j] = *reinterpret_cast<const uint2*>(XsB + (((unsigned)s[j] << 7) + bo));
        #pragma unroll
        for (int j = 0; j < 8; ++j) {
            c0 += bflo(v[j].x); c1 += bfhi(v[j].x); c2 += bflo(v[j].y); c3 += bfhi(v[j].y);
        }
    }

    float dv  = dinv1[dd];
    float dv2 = dinv2[dd];
    uint2 sv = *reinterpret_cast<const uint2*>(XsB + (((unsigned)dd << 7) + bo));
    float h0  = dv * (c0 + bflo(sv.x));
    float h1v = dv * (c1 + bfhi(sv.x));
    float h2  = dv * (c2 + bflo(sv.y));
    float h3  = dv * (c3 + bfhi(sv.y));
    if (active) {
        uint2 o1; o1.x = pk2(h0, h1v); o1.y = pk2(h2, h3);
        *reinterpret_cast<uint2*>(h1 + ((size_t)d << 6) + (fl << 2)) = o1;
        uint2 o2; o2.x = pk2(h0 * dv2, h1v * dv2); o2.y = pk2(h2 * dv2, h3 * dv2);
        *reinterpret_cast<uint2*>(h1s + ((size_t)d << 6) + (fl << 2)) = o2;
    }
}

// ---------------- prop2: 4 nodes/wave, padded CSR + alpha combine ----------------
// out[d] = a0*h1[d] + a1*dinv2[d]*sum(h1s[s])
__global__ __launch_bounds__(256) void prop2_kernel(const int* __restrict__ offsets,
                                                    const unsigned char* __restrict__ npad8,
                                                    const int* __restrict__ sorted_src,
                                                    const unsigned short* __restrict__ h1,
                                                    const unsigned short* __restrict__ h1s,
                                                    const float* __restrict__ dinv2,
                                                    const float* __restrict__ alphas,
                                                    float* __restrict__ out, int N) {
    int wid  = (blockIdx.x * blockDim.x + threadIdx.x) >> 6;
    int lane = threadIdx.x & 63;
    int g = lane >> 4, fl = lane & 15;
    int d = wid * 4 + g;
    bool active = d < N;
    int dd = active ? d : N - 1;

    float e0 = expf(alphas[0]), e1 = expf(alphas[1]);
    float aw0 = e0 / (e0 + e1), aw1 = e1 / (e0 + e1);

    int beg = offsets[dd];
    int nit = npad8[dd];
    const int* idp = sorted_src + beg;
    const char* HB = (const char*)h1s;
    unsigned bo = (unsigned)(fl << 3);
    float c0 = 0.f, c1 = 0.f, c2 = 0.f, c3 = 0.f;

    for (int it = 0; it < nit; ++it, idp += 8) {
        int s[8]; uint2 v[8];
        #pragma unroll
        for (int j = 0; j < 8; ++j) s[j] = idp[j];
        #pragma unroll
        for (int j = 0; j < 8; ++j)
            v[j] = *reinterpret_cast<const uint2*>(HB + (((unsigned)s[j] << 7) + bo));
        #pragma unroll
        for (int j = 0; j < 8; ++j) {
            c0 += bflo(v[j].x); c1 += bfhi(v[j].x); c2 += bflo(v[j].y); c3 += bfhi(v[j].y);
        }
    }

    if (active) {
        float sa1 = aw1 * dinv2[dd];
        uint2 sv = *reinterpret_cast<const uint2*>((const char*)h1 + (((unsigned)d << 7) + bo));
        float4 o;
        o.x = aw0 * bflo(sv.x) + sa1 * c0;
        o.y = aw0 * bfhi(sv.x) + sa1 * c1;
        o.z = aw0 * bflo(sv.y) + sa1 * c2;
        o.w = aw0 * bfhi(sv.y) + sa1 * c3;
        *reinterpret_cast<float4*>(out + ((size_t)d << 6) + (fl << 2)) = o;
    }
}

extern "C" void kernel_launch(void* const* d_in, const int* in_sizes, int n_in,
                              void* d_out, int out_size, void* d_ws, size_t ws_size,
                              hipStream_t stream) {
    const int*   edge_index = (const int*)d_in[0];   // [2, E]
    const float* in_feat    = (const float*)d_in[1]; // [N, 128]
    const float* W1         = (const float*)d_in[2]; // [128, 64]
    const float* alphas     = (const float*)d_in[3]; // [2]
    float*       out        = (float*)d_out;         // [N, 64]

    const int* src = edge_index;
    const int* dst = edge_index + N_EDGES;

    // workspace layout (bf16 tables: (N+16) rows of 64 bf16; row N = zero sentinel)
    char* ws = (char*)d_ws;
    size_t tabBytes = (size_t)(N_NODES + 16) * H_F * 2;
    unsigned short* Xs  = (unsigned short*)(ws);                 // 12.8 MB
    unsigned int*   tmp = (unsigned int*)(ws);                   // 7.84 MB — aliases Xs rows; sentinel untouched
    unsigned short* h1  = (unsigned short*)(ws + tabBytes);      // 12.8 MB
    unsigned short* h1s = (unsigned short*)(ws + 2 * tabBytes);  // 12.8 MB
    char* p = ws + 3 * tabBytes;
    int*   sorted = (int*)p;   p += (size_t)NBKT * SCAP * 4;     // 11.05 MB (per-bucket slack)
    int*   offs   = (int*)p;   p += (size_t)(N_NODES + 4) * 4;
    float* dinv1  = (float*)p; p += (size_t)N_NODES * 4;
    float* dinv2  = (float*)p; p += (size_t)N_NODES * 4;
    unsigned char* npad8 = (unsigned char*)p; p += (size_t)(N_NODES + 64);
    p = (char*)(((size_t)p + 63) & ~(size_t)63);
    int*   ccur   = (int*)p;   p += (size_t)NBKT * 4;
    unsigned int* wfrag = (unsigned int*)p; p += 8192 * 4;       // 32 KB packed W frags

    initwpack_kernel<<<32, 256, 0, stream>>>(W1, wfrag, ccur,
                                             (unsigned int*)(Xs + (size_t)N_NODES * H_F),
                                             (unsigned int*)(h1s + (size_t)N_NODES * H_F));
    coarse_scatter_kernel<<<(N_EDGES + EPB - 1) / EPB, 256, 0, stream>>>(src, dst, ccur, tmp, N_EDGES);
    bucket_kernel<<<NBKT, 512, 0, stream>>>(tmp, ccur, offs, npad8, sorted, dinv1, dinv2, N_NODES);

    // gemm after bucket_kernel (tmp aliases Xs; needs dinv1)
    int nTiles = N_NODES / 16;                        // 6250
    int gemm_waves = (nTiles + 3) / 4;                // 1563
    gemm_kernel<<<(gemm_waves + 3) / 4, 256, 0, stream>>>(in_feat, (const uint4*)wfrag, dinv1, Xs, nTiles);

    int pwaves  = (N_NODES + 3) / 4;                  // 25000 waves, 4 nodes each
    int pblocks = (pwaves + 3) / 4;                   // 6250 blocks of 256
    prop1_kernel<<<pblocks, 256, 0, stream>>>(offs, npad8, sorted, Xs, dinv1, dinv2, h1, h1s, N_NODES);
    prop2_kernel<<<pblocks, 256, 0, stream>>>(offs, npad8, sorted, h1, h1s, dinv2, alphas, out, N_NODES);
}